// Round 6
// baseline (465.606 us; speedup 1.0000x reference)
//
#include <hip/hip_runtime.h>

#define DIM 256  // 2^8 amplitudes

// 5 layer matrices, 4x4 complex each, row-major M[r*4+c]
__device__ float2 g_M[5 * 16];

__device__ inline float2 cmulc(float2 a, float2 b) {
    return make_float2(a.x * b.x - a.y * b.y, a.x * b.y + a.y * b.x);
}
__device__ inline float2 caddc(float2 a, float2 b) {
    return make_float2(a.x + b.x, a.y + b.y);
}

// ---------------- setup: build the 5 SU(4) gate matrices ----------------

__device__ void mat_u3(float t, float p, float l, float2* U) {
    float s, c;
    sincosf(0.5f * t, &s, &c);
    float sp, cp, sl, cl, spl, cpl;
    sincosf(p, &sp, &cp);
    sincosf(l, &sl, &cl);
    sincosf(p + l, &spl, &cpl);
    U[0] = make_float2(c, 0.f);
    U[1] = make_float2(-cl * s, -sl * s);
    U[2] = make_float2(cp * s, sp * s);
    U[3] = make_float2(cpl * c, spl * c);
}
__device__ void mat_ry(float t, float2* U) {
    float s, c;
    sincosf(0.5f * t, &s, &c);
    U[0] = make_float2(c, 0.f); U[1] = make_float2(-s, 0.f);
    U[2] = make_float2(s, 0.f); U[3] = make_float2(c, 0.f);
}
__device__ void mat_rz(float t, float2* U) {
    float s, c;
    sincosf(0.5f * t, &s, &c);
    U[0] = make_float2(c, -s); U[1] = make_float2(0.f, 0.f);
    U[2] = make_float2(0.f, 0.f); U[3] = make_float2(c, s);
}
__device__ void mat_I2(float2* U) {
    U[0] = make_float2(1.f, 0.f); U[1] = make_float2(0.f, 0.f);
    U[2] = make_float2(0.f, 0.f); U[3] = make_float2(1.f, 0.f);
}
__device__ void kron4(const float2* A, const float2* B, float2* K) {
    for (int i0 = 0; i0 < 2; ++i0)
        for (int i1 = 0; i1 < 2; ++i1)
            for (int j0 = 0; j0 < 2; ++j0)
                for (int j1 = 0; j1 < 2; ++j1)
                    K[(2 * i0 + i1) * 4 + (2 * j0 + j1)] = cmulc(A[i0 * 2 + j0], B[i1 * 2 + j1]);
}
__device__ void mm4(const float2* A, const float2* B, float2* C) {
    for (int r = 0; r < 4; ++r)
        for (int c = 0; c < 4; ++c) {
            float2 acc = make_float2(0.f, 0.f);
            for (int k = 0; k < 4; ++k) acc = caddc(acc, cmulc(A[r * 4 + k], B[k * 4 + c]));
            C[r * 4 + c] = acc;
        }
}
__device__ void swap_rows(float2* M, int r1, int r2) {
    for (int c = 0; c < 4; ++c) {
        float2 t = M[r1 * 4 + c]; M[r1 * 4 + c] = M[r2 * 4 + c]; M[r2 * 4 + c] = t;
    }
}

__global__ void qsvdd_setup(const float* __restrict__ w) {
    int l = threadIdx.x;
    if (l >= 5) return;
    const float* p = w + l * 15;
    float2 A[4], Bm[4], K[16], M[16], T[16];
    mat_u3(p[0], p[1], p[2], A);
    mat_u3(p[3], p[4], p[5], Bm);
    kron4(A, Bm, M);
    swap_rows(M, 2, 3);                       // CNOT01 @ M
    mat_ry(p[6], A); mat_rz(p[7], Bm);
    kron4(A, Bm, K); mm4(K, M, T);
    swap_rows(T, 1, 3);                       // CNOT10 @ M
    mat_ry(p[8], A); mat_I2(Bm);
    kron4(A, Bm, K); mm4(K, T, M);
    swap_rows(M, 2, 3);                       // CNOT01 @ M
    mat_u3(p[9], p[10], p[11], A);
    mat_u3(p[12], p[13], p[14], Bm);
    kron4(A, Bm, K); mm4(K, M, T);
    for (int i = 0; i < 16; ++i) g_M[l * 16 + i] = T[i];
}

// ---------------- main: 16 amps/lane, 4 elements per wave ----------------
//
// Amplitude a[7:0]: bits 7..4 = register-index bits r3..r0 (4 LOCAL slots),
// bits 3..0 = lane bits 3..0 (4 lane positions); lane bits 5:4 = element id
// within the wave (4 elems/wave, 16 lanes each). With 4 local bits, most gate
// pairs are register-local: hand-derived schedule needs only 19 swaps per
// wave (serving 4 elements) vs 40/elem in the 2-local-bit version. Gates:
// scalar-FMA 4x4 complex matvec on 4 register quadruples (matrix SGPR-
// resident). Swaps: R2-validated primitive (select + ds_bpermute + selects),
// XOR addresses -> conflict-free.

__device__ __forceinline__ void cmadf(float2& a, float mx, float my, float2 v) {
    a.x = fmaf(mx, v.x, a.x);
    a.x = fmaf(-my, v.y, a.x);
    a.y = fmaf(mx, v.y, a.y);
    a.y = fmaf(my, v.x, a.y);
}
__device__ __forceinline__ float2 cmulf(float mx, float my, float2 v) {
    float2 r;
    r.x = mx * v.x; r.x = fmaf(-my, v.y, r.x);
    r.y = mx * v.y; r.y = fmaf(my, v.x, r.y);
    return r;
}

// 4x4 complex matvec on all 4 quadruples; IP = local slot (reg-index bit) of
// the first tensor factor (pa), IQ = slot of the second (pb).
template <int IP, int IQ>
__device__ __forceinline__ void gate16(float2* v, const float2* M) {
    constexpr int mp = 1 << IP, mq = 1 << IQ;
#pragma unroll
    for (int b = 0; b < 16; ++b) {
        if (b & (mp | mq)) continue;
        const float2 a0 = v[b], a1 = v[b | mq], a2 = v[b | mp], a3 = v[b | mp | mq];
        float2 n0 = cmulf(M[0].x,  M[0].y,  a0);
        cmadf(n0, M[1].x,  M[1].y,  a1); cmadf(n0, M[2].x,  M[2].y,  a2); cmadf(n0, M[3].x,  M[3].y,  a3);
        float2 n1 = cmulf(M[4].x,  M[4].y,  a0);
        cmadf(n1, M[5].x,  M[5].y,  a1); cmadf(n1, M[6].x,  M[6].y,  a2); cmadf(n1, M[7].x,  M[7].y,  a3);
        float2 n2 = cmulf(M[8].x,  M[8].y,  a0);
        cmadf(n2, M[9].x,  M[9].y,  a1); cmadf(n2, M[10].x, M[10].y, a2); cmadf(n2, M[11].x, M[11].y, a3);
        float2 n3 = cmulf(M[12].x, M[12].y, a0);
        cmadf(n3, M[13].x, M[13].y, a1); cmadf(n3, M[14].x, M[14].y, a2); cmadf(n3, M[15].x, M[15].y, a3);
        v[b] = n0; v[b | mq] = n1; v[b | mp] = n2; v[b | mp | mq] = n3;
    }
}

__device__ __forceinline__ float2 bperm2(int ba, float2 s) {
    float2 r;
    r.x = __int_as_float(__builtin_amdgcn_ds_bpermute(ba, __float_as_int(s.x)));
    r.y = __int_as_float(__builtin_amdgcn_ds_bpermute(ba, __float_as_int(s.y)));
    return r;
}

// swap local slot R with a lane bit; pb = own lane-bit value, ba = bpermute
// byte-address of partner lane ((lane ^ mask) << 2 — XOR, conflict-free).
template <int R>
__device__ __forceinline__ void bswap(float2* v, bool pb, int ba) {
    constexpr int m = 1 << R;
#pragma unroll
    for (int j = 0; j < 16; ++j) {
        if (j & m) continue;
        const int j1 = j | m;
        float2 s;
        s.x = pb ? v[j].x : v[j1].x;
        s.y = pb ? v[j].y : v[j1].y;
        const float2 r = bperm2(ba, s);
        v[j].x  = pb ? r.x : v[j].x;
        v[j].y  = pb ? r.y : v[j].y;
        v[j1].x = pb ? v[j1].x : r.x;
        v[j1].y = pb ? v[j1].y : r.y;
    }
}

__global__ __launch_bounds__(256) void qsvdd_main(const float* __restrict__ x,
                                                  float* __restrict__ out) {
    const int lane = threadIdx.x & 63;
    const int q = lane & 15;
    // element id: 4 per wave (lane>>4), 4 waves per block
    const long e = ((long)blockIdx.x * 4 + (threadIdx.x >> 6)) * 4 + (lane >> 4);

    const int ba0 = (lane ^ 1) << 2, ba1 = (lane ^ 2) << 2;
    const int ba2 = (lane ^ 4) << 2, ba3 = (lane ^ 8) << 2;
    const bool p0 = lane & 1, p1 = lane & 2, p2 = lane & 4, p3 = lane & 8;

    // ---- amplitude embedding: a = r*16 + q ----
    const float* xe = x + (e << 8) + q;
    float2 v[16];
#pragma unroll
    for (int r = 0; r < 16; ++r) { v[r].x = xe[r << 4]; v[r].y = 0.f; }
    float ss = 0.f;
#pragma unroll
    for (int r = 0; r < 16; ++r) ss = fmaf(v[r].x, v[r].x, ss);
    ss += __shfl_xor(ss, 1, 64); ss += __shfl_xor(ss, 2, 64);
    ss += __shfl_xor(ss, 4, 64); ss += __shfl_xor(ss, 8, 64);
    const float inv = rsqrtf(ss);
#pragma unroll
    for (int r = 0; r < 16; ++r) v[r].x *= inv;

    float2 Mm[16];
#define LOADM(L)                                                      \
    {                                                                 \
        _Pragma("unroll") for (int i = 0; i < 16; ++i)                \
            Mm[i] = g_M[(L) * 16 + i];                                \
    }

    // ---- schedule; LOC = logical bit per slot, LP = per lane pos ----
    // init LOC=[4,5,6,7], LP=[0,1,2,3]
    LOADM(0);
    // A1: (7,6),(5,4),(3,2),(1,0)
    gate16<3, 2>(v, Mm);                                   // (7,6)
    gate16<1, 0>(v, Mm);                                   // (5,4)
    bswap<3>(v, p3, ba3); bswap<2>(v, p2, ba2);            // LOC=[4,5,2,3]
    bswap<1>(v, p1, ba1); bswap<0>(v, p0, ba0);            // LOC=[0,1,2,3] LP=[4,5,6,7]
    gate16<3, 2>(v, Mm);                                   // (3,2)
    gate16<1, 0>(v, Mm);                                   // (1,0)
    // B1: (2,1),(0,7),(4,3),(6,5)
    gate16<2, 1>(v, Mm);                                   // (2,1)
    bswap<3>(v, p3, ba3);                                  // LOC=[0,1,2,7] LP=[4,5,6,3]
    gate16<0, 3>(v, Mm);                                   // (0,7)
    bswap<1>(v, p3, ba3);                                  // LOC=[0,3,2,7] LP=[4,5,6,1]
    bswap<2>(v, p0, ba0);                                  // LOC=[0,3,4,7] LP=[2,5,6,1]
    gate16<2, 1>(v, Mm);                                   // (4,3)
    bswap<0>(v, p2, ba2);                                  // LOC=[6,3,4,7] LP=[2,5,0,1]
    bswap<3>(v, p1, ba1);                                  // LOC=[6,3,4,5] LP=[2,7,0,1]
    gate16<0, 3>(v, Mm);                                   // (6,5)
    LOADM(1);
    // A2: (5,4),(7,6),(3,2),(1,0)
    gate16<3, 2>(v, Mm);                                   // (5,4)
    bswap<2>(v, p1, ba1);                                  // LOC=[6,3,7,5] LP=[2,4,0,1]
    gate16<2, 0>(v, Mm);                                   // (7,6)
    bswap<3>(v, p0, ba0);                                  // LOC=[6,3,7,2] LP=[5,4,0,1]
    gate16<1, 3>(v, Mm);                                   // (3,2)
    bswap<0>(v, p3, ba3);                                  // LOC=[1,3,7,2] LP=[5,4,0,6]
    bswap<2>(v, p2, ba2);                                  // LOC=[1,3,0,2] LP=[5,4,7,6]
    gate16<0, 2>(v, Mm);                                   // (1,0)
    // B2: (2,1),(0,7),(4,3),(6,5)
    gate16<3, 0>(v, Mm);                                   // (2,1)
    bswap<3>(v, p2, ba2);                                  // LOC=[1,3,0,7] LP=[5,4,2,6]
    gate16<2, 3>(v, Mm);                                   // (0,7)
    bswap<2>(v, p1, ba1);                                  // LOC=[1,3,4,7] LP=[5,0,2,6]
    gate16<2, 1>(v, Mm);                                   // (4,3)
    bswap<0>(v, p3, ba3);                                  // LOC=[6,3,4,7] LP=[5,0,2,1]
    bswap<3>(v, p0, ba0);                                  // LOC=[6,3,4,5] LP=[7,0,2,1]
    gate16<0, 3>(v, Mm);                                   // (6,5)
    LOADM(2);
    // A3: (5,3),(1,7)
    gate16<3, 1>(v, Mm);                                   // (5,3)
    bswap<2>(v, p3, ba3);                                  // LOC=[6,3,1,5] LP=[7,0,2,4]
    bswap<0>(v, p0, ba0);                                  // LOC=[7,3,1,5] LP=[6,0,2,4]
    gate16<2, 0>(v, Mm);                                   // (1,7)
    // B3: (7,5),(3,1)  — all local
    gate16<0, 3>(v, Mm);                                   // (7,5)
    gate16<1, 2>(v, Mm);                                   // (3,1)
    LOADM(3);
    // A4: (5,3),(1,7)
    gate16<3, 1>(v, Mm);                                   // (5,3)
    gate16<2, 0>(v, Mm);                                   // (1,7)
    // B4: (7,5),(3,1)
    gate16<0, 3>(v, Mm);                                   // (7,5)
    gate16<1, 2>(v, Mm);                                   // (3,1)
    LOADM(4);
    // L3: (5,1)
    gate16<3, 2>(v, Mm);                                   // (5,1)
    // final LOC=[7,3,1,5]: bit5 -> reg-bit 3, bit1 -> reg-bit 2

    // ---- expvals: wire2 = bit5 (reg-bit 3), wire6 = bit1 (reg-bit 2) ----
    float n2[16];
#pragma unroll
    for (int r = 0; r < 16; ++r) n2[r] = fmaf(v[r].x, v[r].x, v[r].y * v[r].y);
    float acc[6] = {0.f, 0.f, 0.f, 0.f, 0.f, 0.f};
#pragma unroll
    for (int r = 0; r < 8; ++r) {       // wire2: pairs (r, r+8)
        const float2 a = v[r], b = v[r + 8];
        acc[0] += a.x * b.x + a.y * b.y;
        acc[1] += a.x * b.y - a.y * b.x;
        acc[2] += n2[r] - n2[r + 8];
    }
#pragma unroll
    for (int r = 0; r < 16; ++r) {      // wire6: pairs (r, r|4), bit2(r)==0
        if (r & 4) continue;
        const float2 a = v[r], b = v[r | 4];
        acc[3] += a.x * b.x + a.y * b.y;
        acc[4] += a.x * b.y - a.y * b.x;
        acc[5] += n2[r] - n2[r | 4];
    }
    acc[0] *= 2.f; acc[1] *= 2.f; acc[3] *= 2.f; acc[4] *= 2.f;
#pragma unroll
    for (int k = 0; k < 6; ++k) {
        acc[k] += __shfl_xor(acc[k], 1, 64);
        acc[k] += __shfl_xor(acc[k], 2, 64);
        acc[k] += __shfl_xor(acc[k], 4, 64);
        acc[k] += __shfl_xor(acc[k], 8, 64);
    }
    if (q == 0) {
        float* o = out + e * 6;
        o[0] = acc[0]; o[1] = acc[1]; o[2] = acc[2];
        o[3] = acc[3]; o[4] = acc[4]; o[5] = acc[5];
    }
}

extern "C" void kernel_launch(void* const* d_in, const int* in_sizes, int n_in,
                              void* d_out, int out_size, void* d_ws, size_t ws_size,
                              hipStream_t stream) {
    const float* x = (const float*)d_in[0];
    const float* w = (const float*)d_in[1];
    float* out = (float*)d_out;
    const int B = in_sizes[0] / DIM;  // 32768

    hipLaunchKernelGGL(qsvdd_setup, dim3(1), dim3(64), 0, stream, w);
    // 16 elements per block (4 waves x 4 elems)
    hipLaunchKernelGGL(qsvdd_main, dim3(B / 16), dim3(256), 0, stream, x, out);
}

// Round 7
// 465.079 us; speedup vs baseline: 1.0011x; 1.0011x over previous
//
#include <hip/hip_runtime.h>

#define DIM 256  // 2^8 amplitudes

// 5 layer matrices, 4x4 complex each, row-major M[r*4+c]
__device__ float2 g_M[5 * 16];

__device__ inline float2 cmulc(float2 a, float2 b) {
    return make_float2(a.x * b.x - a.y * b.y, a.x * b.y + a.y * b.x);
}
__device__ inline float2 caddc(float2 a, float2 b) {
    return make_float2(a.x + b.x, a.y + b.y);
}

// ---------------- setup: build the 5 SU(4) gate matrices ----------------

__device__ void mat_u3(float t, float p, float l, float2* U) {
    float s, c;
    sincosf(0.5f * t, &s, &c);
    float sp, cp, sl, cl, spl, cpl;
    sincosf(p, &sp, &cp);
    sincosf(l, &sl, &cl);
    sincosf(p + l, &spl, &cpl);
    U[0] = make_float2(c, 0.f);
    U[1] = make_float2(-cl * s, -sl * s);
    U[2] = make_float2(cp * s, sp * s);
    U[3] = make_float2(cpl * c, spl * c);
}
__device__ void mat_ry(float t, float2* U) {
    float s, c;
    sincosf(0.5f * t, &s, &c);
    U[0] = make_float2(c, 0.f); U[1] = make_float2(-s, 0.f);
    U[2] = make_float2(s, 0.f); U[3] = make_float2(c, 0.f);
}
__device__ void mat_rz(float t, float2* U) {
    float s, c;
    sincosf(0.5f * t, &s, &c);
    U[0] = make_float2(c, -s); U[1] = make_float2(0.f, 0.f);
    U[2] = make_float2(0.f, 0.f); U[3] = make_float2(c, s);
}
__device__ void mat_I2(float2* U) {
    U[0] = make_float2(1.f, 0.f); U[1] = make_float2(0.f, 0.f);
    U[2] = make_float2(0.f, 0.f); U[3] = make_float2(1.f, 0.f);
}
__device__ void kron4(const float2* A, const float2* B, float2* K) {
    for (int i0 = 0; i0 < 2; ++i0)
        for (int i1 = 0; i1 < 2; ++i1)
            for (int j0 = 0; j0 < 2; ++j0)
                for (int j1 = 0; j1 < 2; ++j1)
                    K[(2 * i0 + i1) * 4 + (2 * j0 + j1)] = cmulc(A[i0 * 2 + j0], B[i1 * 2 + j1]);
}
__device__ void mm4(const float2* A, const float2* B, float2* C) {
    for (int r = 0; r < 4; ++r)
        for (int c = 0; c < 4; ++c) {
            float2 acc = make_float2(0.f, 0.f);
            for (int k = 0; k < 4; ++k) acc = caddc(acc, cmulc(A[r * 4 + k], B[k * 4 + c]));
            C[r * 4 + c] = acc;
        }
}
__device__ void swap_rows(float2* M, int r1, int r2) {
    for (int c = 0; c < 4; ++c) {
        float2 t = M[r1 * 4 + c]; M[r1 * 4 + c] = M[r2 * 4 + c]; M[r2 * 4 + c] = t;
    }
}

__global__ void qsvdd_setup(const float* __restrict__ w) {
    int l = threadIdx.x;
    if (l >= 5) return;
    const float* p = w + l * 15;
    float2 A[4], Bm[4], K[16], M[16], T[16];
    mat_u3(p[0], p[1], p[2], A);
    mat_u3(p[3], p[4], p[5], Bm);
    kron4(A, Bm, M);
    swap_rows(M, 2, 3);                       // CNOT01 @ M
    mat_ry(p[6], A); mat_rz(p[7], Bm);
    kron4(A, Bm, K); mm4(K, M, T);
    swap_rows(T, 1, 3);                       // CNOT10 @ M
    mat_ry(p[8], A); mat_I2(Bm);
    kron4(A, Bm, K); mm4(K, T, M);
    swap_rows(M, 2, 3);                       // CNOT01 @ M
    mat_u3(p[9], p[10], p[11], A);
    mat_u3(p[12], p[13], p[14], Bm);
    kron4(A, Bm, K); mm4(K, M, T);
    for (int i = 0; i < 16; ++i) g_M[l * 16 + i] = T[i];
}

// ---------------- main: 16 amps/lane, 4 elements per wave ----------------
//
// Amplitude a[7:0]: bits 7..4 = register-index bits r3..r0 (4 LOCAL slots),
// bits 3..0 = lane bits 3..0; lane bits 5:4 = element id (4 elems/wave).
// 19 swaps per wave serving 4 elements (4.75/elem vs 40/elem in R2).
// R6 spilled to scratch (WRITE_SIZE 547 MB) because the default occupancy
// target capped VGPRs at ~128; __launch_bounds__(256, 1) relaxes the cap
// (min 1 wave/EU -> up to 512 VGPRs) so the 32-VGPR state stays resident.

__device__ __forceinline__ void cmadf(float2& a, float mx, float my, float2 v) {
    a.x = fmaf(mx, v.x, a.x);
    a.x = fmaf(-my, v.y, a.x);
    a.y = fmaf(mx, v.y, a.y);
    a.y = fmaf(my, v.x, a.y);
}
__device__ __forceinline__ float2 cmulf(float mx, float my, float2 v) {
    float2 r;
    r.x = mx * v.x; r.x = fmaf(-my, v.y, r.x);
    r.y = mx * v.y; r.y = fmaf(my, v.x, r.y);
    return r;
}

// 4x4 complex matvec on all 4 quadruples; IP = local slot (reg-index bit) of
// the first tensor factor (pa), IQ = slot of the second (pb).
template <int IP, int IQ>
__device__ __forceinline__ void gate16(float2* v, const float2* M) {
    constexpr int mp = 1 << IP, mq = 1 << IQ;
#pragma unroll
    for (int b = 0; b < 16; ++b) {
        if (b & (mp | mq)) continue;
        const float2 a0 = v[b], a1 = v[b | mq], a2 = v[b | mp], a3 = v[b | mp | mq];
        float2 n0 = cmulf(M[0].x,  M[0].y,  a0);
        cmadf(n0, M[1].x,  M[1].y,  a1); cmadf(n0, M[2].x,  M[2].y,  a2); cmadf(n0, M[3].x,  M[3].y,  a3);
        float2 n1 = cmulf(M[4].x,  M[4].y,  a0);
        cmadf(n1, M[5].x,  M[5].y,  a1); cmadf(n1, M[6].x,  M[6].y,  a2); cmadf(n1, M[7].x,  M[7].y,  a3);
        float2 n2 = cmulf(M[8].x,  M[8].y,  a0);
        cmadf(n2, M[9].x,  M[9].y,  a1); cmadf(n2, M[10].x, M[10].y, a2); cmadf(n2, M[11].x, M[11].y, a3);
        float2 n3 = cmulf(M[12].x, M[12].y, a0);
        cmadf(n3, M[13].x, M[13].y, a1); cmadf(n3, M[14].x, M[14].y, a2); cmadf(n3, M[15].x, M[15].y, a3);
        v[b] = n0; v[b | mq] = n1; v[b | mp] = n2; v[b | mp | mq] = n3;
    }
}

__device__ __forceinline__ float2 bperm2(int ba, float2 s) {
    float2 r;
    r.x = __int_as_float(__builtin_amdgcn_ds_bpermute(ba, __float_as_int(s.x)));
    r.y = __int_as_float(__builtin_amdgcn_ds_bpermute(ba, __float_as_int(s.y)));
    return r;
}

// swap local slot R with a lane bit; pb = own lane-bit value, ba = bpermute
// byte-address of partner lane ((lane ^ mask) << 2 — XOR, conflict-free).
template <int R>
__device__ __forceinline__ void bswap(float2* v, bool pb, int ba) {
    constexpr int m = 1 << R;
#pragma unroll
    for (int j = 0; j < 16; ++j) {
        if (j & m) continue;
        const int j1 = j | m;
        float2 s;
        s.x = pb ? v[j].x : v[j1].x;
        s.y = pb ? v[j].y : v[j1].y;
        const float2 r = bperm2(ba, s);
        v[j].x  = pb ? r.x : v[j].x;
        v[j].y  = pb ? r.y : v[j].y;
        v[j1].x = pb ? v[j1].x : r.x;
        v[j1].y = pb ? v[j1].y : r.y;
    }
}

__global__ __launch_bounds__(256, 1) void qsvdd_main(const float* __restrict__ x,
                                                     float* __restrict__ out) {
    const int lane = threadIdx.x & 63;
    const int q = lane & 15;
    // element id: 4 per wave (lane>>4), 4 waves per block
    const long e = ((long)blockIdx.x * 4 + (threadIdx.x >> 6)) * 4 + (lane >> 4);

    const int ba0 = (lane ^ 1) << 2, ba1 = (lane ^ 2) << 2;
    const int ba2 = (lane ^ 4) << 2, ba3 = (lane ^ 8) << 2;
    const bool p0 = lane & 1, p1 = lane & 2, p2 = lane & 4, p3 = lane & 8;

    // ---- amplitude embedding: a = r*16 + q ----
    const float* xe = x + (e << 8) + q;
    float2 v[16];
#pragma unroll
    for (int r = 0; r < 16; ++r) { v[r].x = xe[r << 4]; v[r].y = 0.f; }
    float ss = 0.f;
#pragma unroll
    for (int r = 0; r < 16; ++r) ss = fmaf(v[r].x, v[r].x, ss);
    ss += __shfl_xor(ss, 1, 64); ss += __shfl_xor(ss, 2, 64);
    ss += __shfl_xor(ss, 4, 64); ss += __shfl_xor(ss, 8, 64);
    const float inv = rsqrtf(ss);
#pragma unroll
    for (int r = 0; r < 16; ++r) v[r].x *= inv;

    float2 Mm[16];
#define LOADM(L)                                                      \
    {                                                                 \
        _Pragma("unroll") for (int i = 0; i < 16; ++i)                \
            Mm[i] = g_M[(L) * 16 + i];                                \
    }

    // ---- schedule; LOC = logical bit per slot, LP = per lane pos ----
    // init LOC=[4,5,6,7], LP=[0,1,2,3]
    LOADM(0);
    // A1: (7,6),(5,4),(3,2),(1,0)
    gate16<3, 2>(v, Mm);                                   // (7,6)
    gate16<1, 0>(v, Mm);                                   // (5,4)
    bswap<3>(v, p3, ba3); bswap<2>(v, p2, ba2);            // LOC=[4,5,2,3]
    bswap<1>(v, p1, ba1); bswap<0>(v, p0, ba0);            // LOC=[0,1,2,3] LP=[4,5,6,7]
    gate16<3, 2>(v, Mm);                                   // (3,2)
    gate16<1, 0>(v, Mm);                                   // (1,0)
    // B1: (2,1),(0,7),(4,3),(6,5)
    gate16<2, 1>(v, Mm);                                   // (2,1)
    bswap<3>(v, p3, ba3);                                  // LOC=[0,1,2,7] LP=[4,5,6,3]
    gate16<0, 3>(v, Mm);                                   // (0,7)
    bswap<1>(v, p3, ba3);                                  // LOC=[0,3,2,7] LP=[4,5,6,1]
    bswap<2>(v, p0, ba0);                                  // LOC=[0,3,4,7] LP=[2,5,6,1]
    gate16<2, 1>(v, Mm);                                   // (4,3)
    bswap<0>(v, p2, ba2);                                  // LOC=[6,3,4,7] LP=[2,5,0,1]
    bswap<3>(v, p1, ba1);                                  // LOC=[6,3,4,5] LP=[2,7,0,1]
    gate16<0, 3>(v, Mm);                                   // (6,5)
    LOADM(1);
    // A2: (5,4),(7,6),(3,2),(1,0)
    gate16<3, 2>(v, Mm);                                   // (5,4)
    bswap<2>(v, p1, ba1);                                  // LOC=[6,3,7,5] LP=[2,4,0,1]
    gate16<2, 0>(v, Mm);                                   // (7,6)
    bswap<3>(v, p0, ba0);                                  // LOC=[6,3,7,2] LP=[5,4,0,1]
    gate16<1, 3>(v, Mm);                                   // (3,2)
    bswap<0>(v, p3, ba3);                                  // LOC=[1,3,7,2] LP=[5,4,0,6]
    bswap<2>(v, p2, ba2);                                  // LOC=[1,3,0,2] LP=[5,4,7,6]
    gate16<0, 2>(v, Mm);                                   // (1,0)
    // B2: (2,1),(0,7),(4,3),(6,5)
    gate16<3, 0>(v, Mm);                                   // (2,1)
    bswap<3>(v, p2, ba2);                                  // LOC=[1,3,0,7] LP=[5,4,2,6]
    gate16<2, 3>(v, Mm);                                   // (0,7)
    bswap<2>(v, p1, ba1);                                  // LOC=[1,3,4,7] LP=[5,0,2,6]
    gate16<2, 1>(v, Mm);                                   // (4,3)
    bswap<0>(v, p3, ba3);                                  // LOC=[6,3,4,7] LP=[5,0,2,1]
    bswap<3>(v, p0, ba0);                                  // LOC=[6,3,4,5] LP=[7,0,2,1]
    gate16<0, 3>(v, Mm);                                   // (6,5)
    LOADM(2);
    // A3: (5,3),(1,7)
    gate16<3, 1>(v, Mm);                                   // (5,3)
    bswap<2>(v, p3, ba3);                                  // LOC=[6,3,1,5] LP=[7,0,2,4]
    bswap<0>(v, p0, ba0);                                  // LOC=[7,3,1,5] LP=[6,0,2,4]
    gate16<2, 0>(v, Mm);                                   // (1,7)
    // B3: (7,5),(3,1)  — all local
    gate16<0, 3>(v, Mm);                                   // (7,5)
    gate16<1, 2>(v, Mm);                                   // (3,1)
    LOADM(3);
    // A4: (5,3),(1,7)
    gate16<3, 1>(v, Mm);                                   // (5,3)
    gate16<2, 0>(v, Mm);                                   // (1,7)
    // B4: (7,5),(3,1)
    gate16<0, 3>(v, Mm);                                   // (7,5)
    gate16<1, 2>(v, Mm);                                   // (3,1)
    LOADM(4);
    // L3: (5,1)
    gate16<3, 2>(v, Mm);                                   // (5,1)
    // final LOC=[7,3,1,5]: bit5 -> reg-bit 3, bit1 -> reg-bit 2

    // ---- expvals: wire2 = bit5 (reg-bit 3), wire6 = bit1 (reg-bit 2) ----
    float n2[16];
#pragma unroll
    for (int r = 0; r < 16; ++r) n2[r] = fmaf(v[r].x, v[r].x, v[r].y * v[r].y);
    float acc[6] = {0.f, 0.f, 0.f, 0.f, 0.f, 0.f};
#pragma unroll
    for (int r = 0; r < 8; ++r) {       // wire2: pairs (r, r+8)
        const float2 a = v[r], b = v[r + 8];
        acc[0] += a.x * b.x + a.y * b.y;
        acc[1] += a.x * b.y - a.y * b.x;
        acc[2] += n2[r] - n2[r + 8];
    }
#pragma unroll
    for (int r = 0; r < 16; ++r) {      // wire6: pairs (r, r|4), bit2(r)==0
        if (r & 4) continue;
        const float2 a = v[r], b = v[r | 4];
        acc[3] += a.x * b.x + a.y * b.y;
        acc[4] += a.x * b.y - a.y * b.x;
        acc[5] += n2[r] - n2[r | 4];
    }
    acc[0] *= 2.f; acc[1] *= 2.f; acc[3] *= 2.f; acc[4] *= 2.f;
#pragma unroll
    for (int k = 0; k < 6; ++k) {
        acc[k] += __shfl_xor(acc[k], 1, 64);
        acc[k] += __shfl_xor(acc[k], 2, 64);
        acc[k] += __shfl_xor(acc[k], 4, 64);
        acc[k] += __shfl_xor(acc[k], 8, 64);
    }
    if (q == 0) {
        float* o = out + e * 6;
        o[0] = acc[0]; o[1] = acc[1]; o[2] = acc[2];
        o[3] = acc[3]; o[4] = acc[4]; o[5] = acc[5];
    }
}

extern "C" void kernel_launch(void* const* d_in, const int* in_sizes, int n_in,
                              void* d_out, int out_size, void* d_ws, size_t ws_size,
                              hipStream_t stream) {
    const float* x = (const float*)d_in[0];
    const float* w = (const float*)d_in[1];
    float* out = (float*)d_out;
    const int B = in_sizes[0] / DIM;  // 32768

    hipLaunchKernelGGL(qsvdd_setup, dim3(1), dim3(64), 0, stream, w);
    // 16 elements per block (4 waves x 4 elems)
    hipLaunchKernelGGL(qsvdd_main, dim3(B / 16), dim3(256), 0, stream, x, out);
}

// Round 8
// 91.754 us; speedup vs baseline: 5.0745x; 5.0687x over previous
//
#include <hip/hip_runtime.h>

#define DIM 256  // 2^8 amplitudes

// 5 layer matrices, 4x4 complex each, row-major M[r*4+c]
__device__ float2 g_M[5 * 16];

__device__ inline float2 cmulc(float2 a, float2 b) {
    return make_float2(a.x * b.x - a.y * b.y, a.x * b.y + a.y * b.x);
}
__device__ inline float2 caddc(float2 a, float2 b) {
    return make_float2(a.x + b.x, a.y + b.y);
}

// ---------------- setup: build the 5 SU(4) gate matrices ----------------

__device__ void mat_u3(float t, float p, float l, float2* U) {
    float s, c;
    sincosf(0.5f * t, &s, &c);
    float sp, cp, sl, cl, spl, cpl;
    sincosf(p, &sp, &cp);
    sincosf(l, &sl, &cl);
    sincosf(p + l, &spl, &cpl);
    U[0] = make_float2(c, 0.f);
    U[1] = make_float2(-cl * s, -sl * s);
    U[2] = make_float2(cp * s, sp * s);
    U[3] = make_float2(cpl * c, spl * c);
}
__device__ void mat_ry(float t, float2* U) {
    float s, c;
    sincosf(0.5f * t, &s, &c);
    U[0] = make_float2(c, 0.f); U[1] = make_float2(-s, 0.f);
    U[2] = make_float2(s, 0.f); U[3] = make_float2(c, 0.f);
}
__device__ void mat_rz(float t, float2* U) {
    float s, c;
    sincosf(0.5f * t, &s, &c);
    U[0] = make_float2(c, -s); U[1] = make_float2(0.f, 0.f);
    U[2] = make_float2(0.f, 0.f); U[3] = make_float2(c, s);
}
__device__ void mat_I2(float2* U) {
    U[0] = make_float2(1.f, 0.f); U[1] = make_float2(0.f, 0.f);
    U[2] = make_float2(0.f, 0.f); U[3] = make_float2(1.f, 0.f);
}
__device__ void kron4(const float2* A, const float2* B, float2* K) {
    for (int i0 = 0; i0 < 2; ++i0)
        for (int i1 = 0; i1 < 2; ++i1)
            for (int j0 = 0; j0 < 2; ++j0)
                for (int j1 = 0; j1 < 2; ++j1)
                    K[(2 * i0 + i1) * 4 + (2 * j0 + j1)] = cmulc(A[i0 * 2 + j0], B[i1 * 2 + j1]);
}
__device__ void mm4(const float2* A, const float2* B, float2* C) {
    for (int r = 0; r < 4; ++r)
        for (int c = 0; c < 4; ++c) {
            float2 acc = make_float2(0.f, 0.f);
            for (int k = 0; k < 4; ++k) acc = caddc(acc, cmulc(A[r * 4 + k], B[k * 4 + c]));
            C[r * 4 + c] = acc;
        }
}
__device__ void swap_rows(float2* M, int r1, int r2) {
    for (int c = 0; c < 4; ++c) {
        float2 t = M[r1 * 4 + c]; M[r1 * 4 + c] = M[r2 * 4 + c]; M[r2 * 4 + c] = t;
    }
}

__global__ void qsvdd_setup(const float* __restrict__ w) {
    int l = threadIdx.x;
    if (l >= 5) return;
    const float* p = w + l * 15;
    float2 A[4], Bm[4], K[16], M[16], T[16];
    mat_u3(p[0], p[1], p[2], A);
    mat_u3(p[3], p[4], p[5], Bm);
    kron4(A, Bm, M);
    swap_rows(M, 2, 3);                       // CNOT01 @ M
    mat_ry(p[6], A); mat_rz(p[7], Bm);
    kron4(A, Bm, K); mm4(K, M, T);
    swap_rows(T, 1, 3);                       // CNOT10 @ M
    mat_ry(p[8], A); mat_I2(Bm);
    kron4(A, Bm, K); mm4(K, T, M);
    swap_rows(M, 2, 3);                       // CNOT01 @ M
    mat_u3(p[9], p[10], p[11], A);
    mat_u3(p[12], p[13], p[14], Bm);
    kron4(A, Bm, K); mm4(K, M, T);
    for (int i = 0; i < 16; ++i) g_M[l * 16 + i] = T[i];
}

// ---------------- main: 16 amps/lane in NAMED registers, 4 elems/wave ----------------
//
// R6/R7: float2 v[16] was demoted to scratch (WRITE_SIZE 566 MB, VALUBusy 16%)
// regardless of __launch_bounds__ — compiler failed to promote the aggregate.
// Fix (guide rule #20): no arrays at all. State = 16 named float2 vars,
// matrix = 16 named vars, every gate/swap/expval macro-expanded over names.
// Schedule identical to R6 (validated correct: passed, absmax 9.8e-4).

__device__ __forceinline__ void cmadf(float2& a, float mx, float my, float2 v) {
    a.x = fmaf(mx, v.x, a.x);
    a.x = fmaf(-my, v.y, a.x);
    a.y = fmaf(mx, v.y, a.y);
    a.y = fmaf(my, v.x, a.y);
}
__device__ __forceinline__ float2 cmulf(float mx, float my, float2 v) {
    float2 r;
    r.x = mx * v.x; r.x = fmaf(-my, v.y, r.x);
    r.y = mx * v.y; r.y = fmaf(my, v.x, r.y);
    return r;
}
__device__ __forceinline__ float bperm(int ba, float s) {
    return __int_as_float(__builtin_amdgcn_ds_bpermute(ba, __float_as_int(s)));
}

// 4x4 complex matvec on one quadruple of named vars (in tensor order a0..a3)
#define GQ(A0, A1, A2, A3)                                                        \
    {                                                                             \
        float2 t0 = cmulf(m0.x, m0.y, A0);                                        \
        cmadf(t0, m1.x, m1.y, A1); cmadf(t0, m2.x, m2.y, A2); cmadf(t0, m3.x, m3.y, A3);   \
        float2 t1 = cmulf(m4.x, m4.y, A0);                                        \
        cmadf(t1, m5.x, m5.y, A1); cmadf(t1, m6.x, m6.y, A2); cmadf(t1, m7.x, m7.y, A3);   \
        float2 t2 = cmulf(m8.x, m8.y, A0);                                        \
        cmadf(t2, m9.x, m9.y, A1); cmadf(t2, m10.x, m10.y, A2); cmadf(t2, m11.x, m11.y, A3); \
        float2 t3 = cmulf(m12.x, m12.y, A0);                                      \
        cmadf(t3, m13.x, m13.y, A1); cmadf(t3, m14.x, m14.y, A2); cmadf(t3, m15.x, m15.y, A3); \
        A0 = t0; A1 = t1; A2 = t2; A3 = t3;                                       \
    }

// gate on local slots (IP,IQ): quadruples (b, b|mq, b|mp, b|mp|mq)
#define G_32 { GQ(v0,v4,v8,v12)  GQ(v1,v5,v9,v13)  GQ(v2,v6,v10,v14) GQ(v3,v7,v11,v15) }
#define G_10 { GQ(v0,v1,v2,v3)   GQ(v4,v5,v6,v7)   GQ(v8,v9,v10,v11) GQ(v12,v13,v14,v15) }
#define G_21 { GQ(v0,v2,v4,v6)   GQ(v1,v3,v5,v7)   GQ(v8,v10,v12,v14) GQ(v9,v11,v13,v15) }
#define G_03 { GQ(v0,v8,v1,v9)   GQ(v2,v10,v3,v11) GQ(v4,v12,v5,v13) GQ(v6,v14,v7,v15) }
#define G_20 { GQ(v0,v1,v4,v5)   GQ(v2,v3,v6,v7)   GQ(v8,v9,v12,v13) GQ(v10,v11,v14,v15) }
#define G_13 { GQ(v0,v8,v2,v10)  GQ(v1,v9,v3,v11)  GQ(v4,v12,v6,v14) GQ(v5,v13,v7,v15) }
#define G_02 { GQ(v0,v4,v1,v5)   GQ(v2,v6,v3,v7)   GQ(v8,v12,v9,v13) GQ(v10,v14,v11,v15) }
#define G_30 { GQ(v0,v1,v8,v9)   GQ(v2,v3,v10,v11) GQ(v4,v5,v12,v13) GQ(v6,v7,v14,v15) }
#define G_23 { GQ(v0,v8,v4,v12)  GQ(v1,v9,v5,v13)  GQ(v2,v10,v6,v14) GQ(v3,v11,v7,v15) }
#define G_31 { GQ(v0,v2,v8,v10)  GQ(v1,v3,v9,v11)  GQ(v4,v6,v12,v14) GQ(v5,v7,v13,v15) }
#define G_12 { GQ(v0,v4,v2,v6)   GQ(v1,v5,v3,v7)   GQ(v8,v12,v10,v14) GQ(v9,v13,v11,v15) }

// swap one register pair with partner lane (select + bpermute + selects)
#define BSW(VA, VB, PB, BA)                                                       \
    {                                                                             \
        float sx = (PB) ? VA.x : VB.x, sy = (PB) ? VA.y : VB.y;                   \
        float rx = bperm(BA, sx), ry = bperm(BA, sy);                             \
        VA.x = (PB) ? rx : VA.x; VA.y = (PB) ? ry : VA.y;                         \
        VB.x = (PB) ? VB.x : rx; VB.y = (PB) ? VB.y : ry;                         \
    }

#define SW0(PB, BA) { BSW(v0,v1,PB,BA) BSW(v2,v3,PB,BA) BSW(v4,v5,PB,BA) BSW(v6,v7,PB,BA) \
                      BSW(v8,v9,PB,BA) BSW(v10,v11,PB,BA) BSW(v12,v13,PB,BA) BSW(v14,v15,PB,BA) }
#define SW1(PB, BA) { BSW(v0,v2,PB,BA) BSW(v1,v3,PB,BA) BSW(v4,v6,PB,BA) BSW(v5,v7,PB,BA) \
                      BSW(v8,v10,PB,BA) BSW(v9,v11,PB,BA) BSW(v12,v14,PB,BA) BSW(v13,v15,PB,BA) }
#define SW2(PB, BA) { BSW(v0,v4,PB,BA) BSW(v1,v5,PB,BA) BSW(v2,v6,PB,BA) BSW(v3,v7,PB,BA) \
                      BSW(v8,v12,PB,BA) BSW(v9,v13,PB,BA) BSW(v10,v14,PB,BA) BSW(v11,v15,PB,BA) }
#define SW3(PB, BA) { BSW(v0,v8,PB,BA) BSW(v1,v9,PB,BA) BSW(v2,v10,PB,BA) BSW(v3,v11,PB,BA) \
                      BSW(v4,v12,PB,BA) BSW(v5,v13,PB,BA) BSW(v6,v14,PB,BA) BSW(v7,v15,PB,BA) }

#define LOADM(L)                                                                  \
    {                                                                             \
        m0  = g_M[(L)*16+0];  m1  = g_M[(L)*16+1];  m2  = g_M[(L)*16+2];  m3  = g_M[(L)*16+3];  \
        m4  = g_M[(L)*16+4];  m5  = g_M[(L)*16+5];  m6  = g_M[(L)*16+6];  m7  = g_M[(L)*16+7];  \
        m8  = g_M[(L)*16+8];  m9  = g_M[(L)*16+9];  m10 = g_M[(L)*16+10]; m11 = g_M[(L)*16+11]; \
        m12 = g_M[(L)*16+12]; m13 = g_M[(L)*16+13]; m14 = g_M[(L)*16+14]; m15 = g_M[(L)*16+15]; \
    }

#define NRM(V) fmaf(V.x, V.x, V.y * V.y)
#define EXP2(A, B) { acc0 += A.x*B.x + A.y*B.y; acc1 += A.x*B.y - A.y*B.x; acc2 += NRM(A) - NRM(B); }
#define EXP6(A, B) { acc3 += A.x*B.x + A.y*B.y; acc4 += A.x*B.y - A.y*B.x; acc5 += NRM(A) - NRM(B); }

__global__ __launch_bounds__(256, 1) void qsvdd_main(const float* __restrict__ x,
                                                     float* __restrict__ out) {
    const int lane = threadIdx.x & 63;
    const int q = lane & 15;
    // element id: 4 per wave (lane>>4), 4 waves per block
    const long e = ((long)blockIdx.x * 4 + (threadIdx.x >> 6)) * 4 + (lane >> 4);

    const int ba0 = (lane ^ 1) << 2, ba1 = (lane ^ 2) << 2;
    const int ba2 = (lane ^ 4) << 2, ba3 = (lane ^ 8) << 2;
    const bool p0 = lane & 1, p1 = lane & 2, p2 = lane & 4, p3 = lane & 8;

    // ---- amplitude embedding: a = r*16 + q ----
    const float* xe = x + (e << 8) + q;
    float2 v0, v1, v2, v3, v4, v5, v6, v7, v8, v9, v10, v11, v12, v13, v14, v15;
    v0.x  = xe[0];   v1.x  = xe[16];  v2.x  = xe[32];  v3.x  = xe[48];
    v4.x  = xe[64];  v5.x  = xe[80];  v6.x  = xe[96];  v7.x  = xe[112];
    v8.x  = xe[128]; v9.x  = xe[144]; v10.x = xe[160]; v11.x = xe[176];
    v12.x = xe[192]; v13.x = xe[208]; v14.x = xe[224]; v15.x = xe[240];
    float ss = 0.f;
    ss = fmaf(v0.x, v0.x, ss);   ss = fmaf(v1.x, v1.x, ss);
    ss = fmaf(v2.x, v2.x, ss);   ss = fmaf(v3.x, v3.x, ss);
    ss = fmaf(v4.x, v4.x, ss);   ss = fmaf(v5.x, v5.x, ss);
    ss = fmaf(v6.x, v6.x, ss);   ss = fmaf(v7.x, v7.x, ss);
    ss = fmaf(v8.x, v8.x, ss);   ss = fmaf(v9.x, v9.x, ss);
    ss = fmaf(v10.x, v10.x, ss); ss = fmaf(v11.x, v11.x, ss);
    ss = fmaf(v12.x, v12.x, ss); ss = fmaf(v13.x, v13.x, ss);
    ss = fmaf(v14.x, v14.x, ss); ss = fmaf(v15.x, v15.x, ss);
    ss += __shfl_xor(ss, 1, 64); ss += __shfl_xor(ss, 2, 64);
    ss += __shfl_xor(ss, 4, 64); ss += __shfl_xor(ss, 8, 64);
    const float inv = rsqrtf(ss);
    v0.x *= inv;  v1.x *= inv;  v2.x *= inv;  v3.x *= inv;
    v4.x *= inv;  v5.x *= inv;  v6.x *= inv;  v7.x *= inv;
    v8.x *= inv;  v9.x *= inv;  v10.x *= inv; v11.x *= inv;
    v12.x *= inv; v13.x *= inv; v14.x *= inv; v15.x *= inv;
    v0.y = 0.f;  v1.y = 0.f;  v2.y = 0.f;  v3.y = 0.f;
    v4.y = 0.f;  v5.y = 0.f;  v6.y = 0.f;  v7.y = 0.f;
    v8.y = 0.f;  v9.y = 0.f;  v10.y = 0.f; v11.y = 0.f;
    v12.y = 0.f; v13.y = 0.f; v14.y = 0.f; v15.y = 0.f;

    float2 m0, m1, m2, m3, m4, m5, m6, m7, m8, m9, m10, m11, m12, m13, m14, m15;

    // ---- schedule (identical to R6, validated) ----
    LOADM(0);
    // A1: (7,6),(5,4),(3,2),(1,0)
    G_32; G_10;
    SW3(p3, ba3); SW2(p2, ba2); SW1(p1, ba1); SW0(p0, ba0);
    G_32; G_10;
    // B1: (2,1),(0,7),(4,3),(6,5)
    G_21;
    SW3(p3, ba3);
    G_03;
    SW1(p3, ba3); SW2(p0, ba0);
    G_21;
    SW0(p2, ba2); SW3(p1, ba1);
    G_03;
    LOADM(1);
    // A2: (5,4),(7,6),(3,2),(1,0)
    G_32;
    SW2(p1, ba1);
    G_20;
    SW3(p0, ba0);
    G_13;
    SW0(p3, ba3); SW2(p2, ba2);
    G_02;
    // B2: (2,1),(0,7),(4,3),(6,5)
    G_30;
    SW3(p2, ba2);
    G_23;
    SW2(p1, ba1);
    G_21;
    SW0(p3, ba3); SW3(p0, ba0);
    G_03;
    LOADM(2);
    // A3: (5,3),(1,7)
    G_31;
    SW2(p3, ba3); SW0(p0, ba0);
    G_20;
    // B3: (7,5),(3,1) — all local
    G_03; G_12;
    LOADM(3);
    // A4: (5,3),(1,7)
    G_31; G_20;
    // B4: (7,5),(3,1)
    G_03; G_12;
    LOADM(4);
    // L3: (5,1)
    G_32;
    // final: bit5 -> reg-bit 3, bit1 -> reg-bit 2

    // ---- expvals: wire2 = reg-bit 3 pairs, wire6 = reg-bit 2 pairs ----
    float acc0 = 0.f, acc1 = 0.f, acc2 = 0.f, acc3 = 0.f, acc4 = 0.f, acc5 = 0.f;
    EXP2(v0, v8)  EXP2(v1, v9)  EXP2(v2, v10)  EXP2(v3, v11)
    EXP2(v4, v12) EXP2(v5, v13) EXP2(v6, v14)  EXP2(v7, v15)
    EXP6(v0, v4)  EXP6(v1, v5)  EXP6(v2, v6)   EXP6(v3, v7)
    EXP6(v8, v12) EXP6(v9, v13) EXP6(v10, v14) EXP6(v11, v15)
    acc0 *= 2.f; acc1 *= 2.f; acc3 *= 2.f; acc4 *= 2.f;
    acc0 += __shfl_xor(acc0, 1, 64); acc0 += __shfl_xor(acc0, 2, 64);
    acc0 += __shfl_xor(acc0, 4, 64); acc0 += __shfl_xor(acc0, 8, 64);
    acc1 += __shfl_xor(acc1, 1, 64); acc1 += __shfl_xor(acc1, 2, 64);
    acc1 += __shfl_xor(acc1, 4, 64); acc1 += __shfl_xor(acc1, 8, 64);
    acc2 += __shfl_xor(acc2, 1, 64); acc2 += __shfl_xor(acc2, 2, 64);
    acc2 += __shfl_xor(acc2, 4, 64); acc2 += __shfl_xor(acc2, 8, 64);
    acc3 += __shfl_xor(acc3, 1, 64); acc3 += __shfl_xor(acc3, 2, 64);
    acc3 += __shfl_xor(acc3, 4, 64); acc3 += __shfl_xor(acc3, 8, 64);
    acc4 += __shfl_xor(acc4, 1, 64); acc4 += __shfl_xor(acc4, 2, 64);
    acc4 += __shfl_xor(acc4, 4, 64); acc4 += __shfl_xor(acc4, 8, 64);
    acc5 += __shfl_xor(acc5, 1, 64); acc5 += __shfl_xor(acc5, 2, 64);
    acc5 += __shfl_xor(acc5, 4, 64); acc5 += __shfl_xor(acc5, 8, 64);
    if (q == 0) {
        float* o = out + e * 6;
        o[0] = acc0; o[1] = acc1; o[2] = acc2;
        o[3] = acc3; o[4] = acc4; o[5] = acc5;
    }
}

extern "C" void kernel_launch(void* const* d_in, const int* in_sizes, int n_in,
                              void* d_out, int out_size, void* d_ws, size_t ws_size,
                              hipStream_t stream) {
    const float* x = (const float*)d_in[0];
    const float* w = (const float*)d_in[1];
    float* out = (float*)d_out;
    const int B = in_sizes[0] / DIM;  // 32768

    hipLaunchKernelGGL(qsvdd_setup, dim3(1), dim3(64), 0, stream, w);
    // 16 elements per block (4 waves x 4 elems)
    hipLaunchKernelGGL(qsvdd_main, dim3(B / 16), dim3(256), 0, stream, x, out);
}